// Round 1
// baseline (1254.584 us; speedup 1.0000x reference)
//
#include <hip/hip_runtime.h>
#include <math.h>

#define B_    4
#define N_    4096
#define C_    512
#define KSLOT 683

// d_out layout (floats), concatenated in reference return order
#define OFF_A    0
#define OFF_SC   (B_*N_*KSLOT)              // 11190272
#define OFF_MU   (OFF_SC + B_*KSLOT*C_)     // 12589056
#define OFF_SIG  (OFF_MU + B_*KSLOT*3)      // 12597252
#define OFF_LOSS (OFF_SIG + B_*KSLOT*9)     // 12621840

// workspace layout (floats)
#define WS_MOM    0                          // B*K*16 accumulators
#define WS_INVMAX (WS_MOM + B_*KSLOT*16)     // 43712
#define WS_OCCTB  (WS_INVMAX + B_*KSLOT)     // 46444 (256 bins, b*64+lane)
#define WS_OCCT   (WS_OCCTB + 256)           // 46700 (4)
#define WS_ENTB   (WS_OCCT + 4)              // 46704 (256 bins)
#define WS_MSB    (WS_ENTB + 256)            // 46960 (256 bins)
#define WS_OCCLB  (WS_MSB + 256)             // 47216 (256 bins)
#define WS_REPB   (WS_OCCLB + 256)           // 47472 (256 bins)
#define WS_TOTAL  (WS_REPB + 256)            // 47728 floats

// ---------------- helpers ----------------

__device__ __forceinline__ float blockSum256(float v, float* red) {
#pragma unroll
  for (int off = 32; off; off >>= 1) v += __shfl_xor(v, off);
  __syncthreads();
  if ((threadIdx.x & 63) == 0) red[threadIdx.x >> 6] = v;
  __syncthreads();
  return red[0] + red[1] + red[2] + red[3];
}

__device__ __forceinline__ void top4_insert(float v, float& t0, float& t1, float& t2, float& t3) {
  if (v > t3) {
    if (v > t2) {
      t3 = t2;
      if (v > t1) {
        t2 = t1;
        if (v > t0) { t1 = t0; t0 = v; } else t1 = v;
      } else t2 = v;
    } else t3 = v;
  }
}

// ---------------- Wsl = slots @ W  (folded linear) ----------------
// Wsl[k,c] = sum_d slots[k,d] * W[d,c]
__global__ __launch_bounds__(256) void wslots_kernel(const float* __restrict__ slots,
                                                     const float* __restrict__ W,
                                                     float* __restrict__ Wsl) {
  int k = blockIdx.x;
  int c = blockIdx.y * 256 + threadIdx.x;
  const float* srow = slots + (size_t)k * C_;
  float acc = 0.f;
  for (int d = 0; d < C_; d += 4) {
    float s0 = srow[d], s1 = srow[d + 1], s2 = srow[d + 2], s3 = srow[d + 3];
    acc += s0 * W[(size_t)d * C_ + c];
    acc += s1 * W[(size_t)(d + 1) * C_ + c];
    acc += s2 * W[(size_t)(d + 2) * C_ + c];
    acc += s3 * W[(size_t)(d + 3) * C_ + c];
  }
  Wsl[(size_t)k * C_ + c] = acc;
}

// bs[k] = sum_d slots[k,d] * b[d]
__global__ __launch_bounds__(256) void bs_kernel(const float* __restrict__ slots,
                                                 const float* __restrict__ bvec,
                                                 float* __restrict__ bs) {
  int k = blockIdx.x * 256 + threadIdx.x;
  if (k >= KSLOT) return;
  const float* srow = slots + (size_t)k * C_;
  float acc = 0.f;
  for (int d = 0; d < C_; ++d) acc += srow[d] * bvec[d];
  bs[k] = acc;
}

// ---------------- NT GEMM: C[m,n] = sum_k A[m,k]*Bm[n,k] + bias[n] ----------------
// BM=128 BN=128 BK=16, 256 threads, 8x8 per thread
__global__ __launch_bounds__(256) void gemm_nt(const float* __restrict__ Am,
                                               const float* __restrict__ Bm,
                                               const float* __restrict__ bias,
                                               float* __restrict__ Cm,
                                               int M, int Nout, int Kd,
                                               int lda, int ldb, int ldc) {
  __shared__ float As[16][132];
  __shared__ float Bs[16][132];
  const int tid = threadIdx.x;
  const int tx = tid & 15, ty = tid >> 4;
  const int m0 = blockIdx.x * 128, n0 = blockIdx.y * 128;
  float acc[8][8];
#pragma unroll
  for (int i = 0; i < 8; ++i)
#pragma unroll
    for (int j = 0; j < 8; ++j) acc[i][j] = 0.f;

  const int r = tid >> 1, hc = (tid & 1) * 8;
  for (int k0 = 0; k0 < Kd; k0 += 16) {
    float va[8], vb[8];
    int gm = m0 + r;
    if (gm < M) {
      const float* p = Am + (size_t)gm * lda + k0 + hc;
      *(float4*)(va)     = *(const float4*)(p);
      *(float4*)(va + 4) = *(const float4*)(p + 4);
    } else {
#pragma unroll
      for (int i = 0; i < 8; ++i) va[i] = 0.f;
    }
    int gn = n0 + r;
    if (gn < Nout) {
      const float* p = Bm + (size_t)gn * ldb + k0 + hc;
      *(float4*)(vb)     = *(const float4*)(p);
      *(float4*)(vb + 4) = *(const float4*)(p + 4);
    } else {
#pragma unroll
      for (int i = 0; i < 8; ++i) vb[i] = 0.f;
    }
#pragma unroll
    for (int i = 0; i < 8; ++i) As[hc + i][r] = va[i];
#pragma unroll
    for (int i = 0; i < 8; ++i) Bs[hc + i][r] = vb[i];
    __syncthreads();
#pragma unroll
    for (int kk = 0; kk < 16; ++kk) {
      float a[8], bb[8];
      *(float4*)(a)      = *(const float4*)&As[kk][ty * 8];
      *(float4*)(a + 4)  = *(const float4*)&As[kk][ty * 8 + 4];
      *(float4*)(bb)     = *(const float4*)&Bs[kk][tx * 8];
      *(float4*)(bb + 4) = *(const float4*)&Bs[kk][tx * 8 + 4];
#pragma unroll
      for (int i = 0; i < 8; ++i)
#pragma unroll
        for (int j = 0; j < 8; ++j) acc[i][j] += a[i] * bb[j];
    }
    __syncthreads();
  }
#pragma unroll
  for (int i = 0; i < 8; ++i) {
    int gm = m0 + ty * 8 + i;
    if (gm >= M) continue;
    float* crow = Cm + (size_t)gm * ldc;
#pragma unroll
    for (int j = 0; j < 8; ++j) {
      int gn = n0 + tx * 8 + j;
      if (gn < Nout) crow[gn] = acc[i][j] + bias[gn];
    }
  }
}

// ---------------- masked softmax over K + entropy accumulation (in place) ----------------
__global__ __launch_bounds__(256) void softmax_rows(float* __restrict__ Amat,
                                                    const float* __restrict__ mask,
                                                    float* __restrict__ entb,
                                                    float* __restrict__ msb) {
  __shared__ float red[4];
  const int row = blockIdx.x;
  const int tid = threadIdx.x;
  float* rowp = Amat + (size_t)row * KSLOT;
  const float m = mask[row];
  const bool msk = (m < 0.5f);
  float v[3];
#pragma unroll
  for (int i = 0; i < 3; ++i) {
    int k = tid + i * 256;
    if (k < KSLOT) {
      float l = rowp[k];
      v[i] = msk ? -1e9f : l;
    } else v[i] = -3.0e38f;
  }
  float lmax = fmaxf(fmaxf(v[0], v[1]), v[2]);
#pragma unroll
  for (int off = 32; off; off >>= 1) lmax = fmaxf(lmax, __shfl_xor(lmax, off));
  __syncthreads();
  if ((tid & 63) == 0) red[tid >> 6] = lmax;
  __syncthreads();
  lmax = fmaxf(fmaxf(red[0], red[1]), fmaxf(red[2], red[3]));

  float lsum = 0.f;
#pragma unroll
  for (int i = 0; i < 3; ++i) {
    int k = tid + i * 256;
    float e = (k < KSLOT) ? expf(v[i] - lmax) : 0.f;
    v[i] = e;
    lsum += e;
  }
  lsum = blockSum256(lsum, red);
  float inv = 1.f / lsum;
  float ent = 0.f;
#pragma unroll
  for (int i = 0; i < 3; ++i) {
    int k = tid + i * 256;
    if (k < KSLOT) {
      float a = v[i] * inv * m;
      rowp[k] = a;
      float ac = fmaxf(a, 1e-8f);
      ent -= ac * logf(ac);
    }
  }
  ent = blockSum256(ent, red);
  if (tid == 0) {
    int bin = blockIdx.x & 255;
    atomicAdd(&entb[bin], ent * m);
    atomicAdd(&msb[bin], m);
  }
}

// ---------------- moment accumulation: MOM[b,k][16] = sum_n A*{1,mu,mu⊗mu,Sigma6} ----------------
__global__ __launch_bounds__(256) void moments_kernel(const float* __restrict__ Amat,
                                                      const float* __restrict__ mu,
                                                      const float* __restrict__ Sig,
                                                      float* __restrict__ MOM) {
  const int b = blockIdx.z;
  const int kx = threadIdx.x & 63;
  const int k = blockIdx.x * 64 + kx;
  const int ng = threadIdx.x >> 6;  // 0..3
  const int n0 = blockIdx.y * 256;
  const bool valid = (k < KSLOT);
  float acc[16];
#pragma unroll
  for (int i = 0; i < 16; ++i) acc[i] = 0.f;

  for (int nn = ng; nn < 256; nn += 4) {
    const int n = n0 + nn;
    const float a = valid ? Amat[((size_t)b * N_ + n) * KSLOT + k] : 0.f;
    const float* mup = mu + ((size_t)b * N_ + n) * 3;
    const float m0v = mup[0], m1v = mup[1], m2v = mup[2];
    const float* sp = Sig + ((size_t)b * N_ + n) * 9;
    acc[0] += a;
    acc[1] += a * m0v; acc[2] += a * m1v; acc[3] += a * m2v;
    acc[4] += a * m0v * m0v; acc[5] += a * m0v * m1v; acc[6] += a * m0v * m2v;
    acc[7] += a * m1v * m1v; acc[8] += a * m1v * m2v; acc[9] += a * m2v * m2v;
    acc[10] += a * sp[0]; acc[11] += a * sp[1]; acc[12] += a * sp[2];
    acc[13] += a * sp[4]; acc[14] += a * sp[5]; acc[15] += a * sp[8];
  }
  __shared__ float red[64][16];
  if (ng == 0) {
#pragma unroll
    for (int i = 0; i < 16; ++i) red[kx][i] = acc[i];
  }
  __syncthreads();
  if (ng == 1) {
#pragma unroll
    for (int i = 0; i < 16; ++i) red[kx][i] += acc[i];
  }
  __syncthreads();
  if (ng == 2) {
#pragma unroll
    for (int i = 0; i < 16; ++i) red[kx][i] += acc[i];
  }
  __syncthreads();
  if (ng == 3) {
#pragma unroll
    for (int i = 0; i < 16; ++i) red[kx][i] += acc[i];
  }
  __syncthreads();
  if (ng == 0 && valid) {
    float* dst = MOM + ((size_t)b * KSLOT + k) * 16;
#pragma unroll
    for (int i = 0; i < 16; ++i) atomicAdd(&dst[i], red[kx][i]);
  }
}

// ---------------- finalize per (b,k): mu_c, Sigma_c, invmax, occ bins ----------------
__global__ __launch_bounds__(256) void finalize_bk(const float* __restrict__ MOM,
                                                   float* __restrict__ muc,
                                                   float* __restrict__ sigc,
                                                   float* __restrict__ invmax,
                                                   float* __restrict__ occtb) {
  int bk = blockIdx.x * 256 + threadIdx.x;
  if (bk >= B_ * KSLOT) return;
  int b = bk / KSLOT;
  const float* T = MOM + (size_t)bk * 16;
  float den = T[0];
  float inv_eps = 1.f / (den + 1e-8f);
  float inv_mx = 1.f / fmaxf(den, 1e-8f);
  float mc0 = T[1] * inv_eps, mc1 = T[2] * inv_eps, mc2 = T[3] * inv_eps;
  float M0 = den * inv_eps;
  float cf = 2.f - M0;
  float S00 = (T[10] + T[4]) * inv_eps - cf * mc0 * mc0;
  float S01 = (T[11] + T[5]) * inv_eps - cf * mc0 * mc1;
  float S02 = (T[12] + T[6]) * inv_eps - cf * mc0 * mc2;
  float S11 = (T[13] + T[7]) * inv_eps - cf * mc1 * mc1;
  float S12 = (T[14] + T[8]) * inv_eps - cf * mc1 * mc2;
  float S22 = (T[15] + T[9]) * inv_eps - cf * mc2 * mc2;
  muc[(size_t)bk * 3 + 0] = mc0;
  muc[(size_t)bk * 3 + 1] = mc1;
  muc[(size_t)bk * 3 + 2] = mc2;
  float* sg = sigc + (size_t)bk * 9;
  sg[0] = S00; sg[1] = S01; sg[2] = S02;
  sg[3] = S01; sg[4] = S11; sg[5] = S12;
  sg[6] = S02; sg[7] = S12; sg[8] = S22;
  invmax[bk] = inv_mx;
  atomicAdd(&occtb[b * 64 + (threadIdx.x & 63)], den);
}

__global__ void reduce_occT(const float* __restrict__ bins, float* __restrict__ occT) {
  int tid = threadIdx.x;  // 256
  float v = bins[tid];
#pragma unroll
  for (int off = 32; off; off >>= 1) v += __shfl_xor(v, off);
  if ((tid & 63) == 0) occT[tid >> 6] = v;
}

__global__ __launch_bounds__(256) void occ_loss_kernel(const float* __restrict__ MOM,
                                                       const float* __restrict__ occT,
                                                       float* __restrict__ occlb) {
  __shared__ float red[4];
  int bk = blockIdx.x * 256 + threadIdx.x;
  float d2 = 0.f;
  if (bk < B_ * KSLOT) {
    int b = bk / KSLOT;
    float den = MOM[(size_t)bk * 16];
    float occ = den / fmaxf(occT[b], 1e-8f);
    float d = occ - (1.f / (float)KSLOT);
    d2 = d * d;
  }
  float ssum = blockSum256(d2, red);
  if (threadIdx.x == 0) occlb[blockIdx.x] = ssum;
}

// ---------------- TN GEMM: C[m,n] = scale[m] * sum_r A[r,m]*Bv[r,n]  (per batch) ----------------
// BM=128 BN=64 BK=16, 256 threads, 8x4 per thread
__global__ __launch_bounds__(256) void gemm_tn(const float* __restrict__ Aall,
                                               const float* __restrict__ Ball,
                                               const float* __restrict__ scale,
                                               float* __restrict__ Call) {
  const int b = blockIdx.z;
  const float* Am = Aall + (size_t)b * N_ * KSLOT;
  const float* Bv = Ball + (size_t)b * N_ * C_;
  float* Cm = Call + (size_t)b * KSLOT * C_;
  const float* sc = scale + (size_t)b * KSLOT;
  __shared__ float As[16][132];
  __shared__ float Bs[16][68];
  const int tid = threadIdx.x;
  const int tx = tid & 15, ty = tid >> 4;
  const int m0 = blockIdx.x * 128, n0 = blockIdx.y * 64;
  float acc[8][4];
#pragma unroll
  for (int i = 0; i < 8; ++i)
#pragma unroll
    for (int j = 0; j < 4; ++j) acc[i][j] = 0.f;

  const int rr = tid >> 4;        // 0..15 (reduction row)
  const int mq = tid & 15;        // 0..15
  const int cq = (tid & 15) * 4;
  for (int r0 = 0; r0 < N_; r0 += 16) {
#pragma unroll
    for (int i = 0; i < 8; ++i) {
      int mm = mq + 16 * i;
      int gm = m0 + mm;
      As[rr][mm] = (gm < KSLOT) ? Am[(size_t)(r0 + rr) * KSLOT + gm] : 0.f;
    }
    *(float4*)&Bs[rr][cq] = *(const float4*)(Bv + (size_t)(r0 + rr) * C_ + n0 + cq);
    __syncthreads();
#pragma unroll
    for (int kk = 0; kk < 16; ++kk) {
      float a[8], bb[4];
      *(float4*)(a)     = *(const float4*)&As[kk][ty * 8];
      *(float4*)(a + 4) = *(const float4*)&As[kk][ty * 8 + 4];
      *(float4*)(bb)    = *(const float4*)&Bs[kk][tx * 4];
#pragma unroll
      for (int i = 0; i < 8; ++i)
#pragma unroll
        for (int j = 0; j < 4; ++j) acc[i][j] += a[i] * bb[j];
    }
    __syncthreads();
  }
#pragma unroll
  for (int i = 0; i < 8; ++i) {
    int gm = m0 + ty * 8 + i;
    if (gm < KSLOT) {
      float s = sc[gm];
      float4 v;
      v.x = acc[i][0] * s; v.y = acc[i][1] * s; v.z = acc[i][2] * s; v.w = acc[i][3] * s;
      *(float4*)(Cm + (size_t)gm * C_ + n0 + tx * 4) = v;
    }
  }
}

// ---------------- repulsion: top-4 pairwise Gaussian overlap per (b,p) ----------------
__global__ __launch_bounds__(256) void repulsion_kernel(const float* __restrict__ muc,
                                                        const float* __restrict__ sigc,
                                                        float* __restrict__ repb) {
  const int bp = blockIdx.x;
  const int b = bp / KSLOT;
  const int p = bp - b * KSLOT;
  const int tid = threadIdx.x;
  const float mp0 = muc[(size_t)bp * 3 + 0];
  const float mp1 = muc[(size_t)bp * 3 + 1];
  const float mp2 = muc[(size_t)bp * 3 + 2];
  const float* sgp = sigc + (size_t)bp * 9;
  const float pa = sgp[0], pb = sgp[1], pc = sgp[2], pd = sgp[4], pe = sgp[5], pf = sgp[8];
  float t0 = -3e38f, t1 = -3e38f, t2 = -3e38f, t3 = -3e38f;
  for (int q = tid; q < KSLOT; q += 256) {
    if (q == p) continue;
    const int bq = b * KSLOT + q;
    float d0 = mp0 - muc[(size_t)bq * 3 + 0];
    float d1 = mp1 - muc[(size_t)bq * 3 + 1];
    float d2 = mp2 - muc[(size_t)bq * 3 + 2];
    const float* sgq = sigc + (size_t)bq * 9;
    float a = pa + sgq[0] + 1e-6f;
    float bb = pb + sgq[1];
    float cc = pc + sgq[2];
    float d = pd + sgq[4] + 1e-6f;
    float e = pe + sgq[5];
    float f = pf + sgq[8] + 1e-6f;
    float C00 = d * f - e * e;
    float C01 = cc * e - bb * f;
    float C02 = bb * e - cc * d;
    float C11 = a * f - cc * cc;
    float C12 = bb * cc - a * e;
    float C22 = a * d - bb * bb;
    float det = a * C00 + bb * C01 + cc * C02;
    float dist2 = (C00 * d0 * d0 + C11 * d1 * d1 + C22 * d2 * d2 +
                   2.f * (C01 * d0 * d1 + C02 * d0 * d2 + C12 * d1 * d2)) / det;
    top4_insert(-0.5f * dist2, t0, t1, t2, t3);
  }
  __shared__ float tl[256][4];
  __shared__ float wl[4][4];
  tl[tid][0] = t0; tl[tid][1] = t1; tl[tid][2] = t2; tl[tid][3] = t3;
  __syncthreads();
  if ((tid & 63) == 0) {
    int w = tid >> 6;
    float u0 = -3e38f, u1 = -3e38f, u2 = -3e38f, u3 = -3e38f;
    for (int i = w * 64; i < w * 64 + 64; ++i) {
      top4_insert(tl[i][0], u0, u1, u2, u3);
      top4_insert(tl[i][1], u0, u1, u2, u3);
      top4_insert(tl[i][2], u0, u1, u2, u3);
      top4_insert(tl[i][3], u0, u1, u2, u3);
    }
    wl[w][0] = u0; wl[w][1] = u1; wl[w][2] = u2; wl[w][3] = u3;
  }
  __syncthreads();
  if (tid == 0) {
    float u0 = -3e38f, u1 = -3e38f, u2 = -3e38f, u3 = -3e38f;
#pragma unroll
    for (int w = 0; w < 4; ++w)
#pragma unroll
      for (int j = 0; j < 4; ++j) top4_insert(wl[w][j], u0, u1, u2, u3);
    float s = fmaxf(u0 + 1.f, 0.f) + fmaxf(u1 + 1.f, 0.f) +
              fmaxf(u2 + 1.f, 0.f) + fmaxf(u3 + 1.f, 0.f);
    atomicAdd(&repb[blockIdx.x & 255], s);
  }
}

// ---------------- final scalars ----------------
__global__ __launch_bounds__(256) void final_scalars(const float* __restrict__ entb,
                                                     const float* __restrict__ msb,
                                                     const float* __restrict__ occlb,
                                                     const float* __restrict__ repb,
                                                     float* __restrict__ out) {
  __shared__ float red[4];
  int tid = threadIdx.x;
  float e = blockSum256(entb[tid], red);
  float ms = blockSum256(msb[tid], red);
  float oc = blockSum256(occlb[tid], red);
  float rp = blockSum256(repb[tid], red);
  if (tid == 0) {
    float loss_ent = e / fmaxf(ms, 1.f);
    float loss_occ = oc / (float)(B_ * KSLOT);
    float loss_rep = rp / (float)(B_ * KSLOT * 4);
    out[0] = loss_occ;
    out[1] = loss_rep;
    out[2] = loss_ent;
    out[3] = 1.0f * loss_occ + 0.1f * loss_rep + 0.01f * loss_ent;
  }
}

// ---------------- launch ----------------
extern "C" void kernel_launch(void* const* d_in, const int* in_sizes, int n_in,
                              void* d_out, int out_size, void* d_ws, size_t ws_size,
                              hipStream_t stream) {
  const float* s     = (const float*)d_in[0];
  const float* mu    = (const float*)d_in[1];
  const float* Sig   = (const float*)d_in[2];
  const float* mask  = (const float*)d_in[3];
  const float* W     = (const float*)d_in[4];
  const float* bvec  = (const float*)d_in[5];
  const float* slots = (const float*)d_in[6];
  float* out = (float*)d_out;
  float* ws  = (float*)d_ws;

  float* Amat = out + OFF_A;
  float* Wsl  = out + OFF_SC;                       // scratch: overwritten later by s_c
  float* bs   = out + OFF_SC + (size_t)KSLOT * C_;  // scratch in s_c region (batch 1 area)

  (void)hipMemsetAsync(ws, 0, WS_TOTAL * sizeof(float), stream);

  wslots_kernel<<<dim3(KSLOT, 2), 256, 0, stream>>>(slots, W, Wsl);
  bs_kernel<<<dim3(3), 256, 0, stream>>>(slots, bvec, bs);

  // logits -> A region
  gemm_nt<<<dim3((B_ * N_) / 128, (KSLOT + 127) / 128), 256, 0, stream>>>(
      s, Wsl, bs, Amat, B_ * N_, KSLOT, C_, C_, C_, KSLOT);

  softmax_rows<<<dim3(B_ * N_), 256, 0, stream>>>(Amat, mask, ws + WS_ENTB, ws + WS_MSB);

  moments_kernel<<<dim3((KSLOT + 63) / 64, N_ / 256, B_), 256, 0, stream>>>(
      Amat, mu, Sig, ws + WS_MOM);

  finalize_bk<<<dim3((B_ * KSLOT + 255) / 256), 256, 0, stream>>>(
      ws + WS_MOM, out + OFF_MU, out + OFF_SIG, ws + WS_INVMAX, ws + WS_OCCTB);

  reduce_occT<<<dim3(1), 256, 0, stream>>>(ws + WS_OCCTB, ws + WS_OCCT);

  occ_loss_kernel<<<dim3((B_ * KSLOT + 255) / 256), 256, 0, stream>>>(
      ws + WS_MOM, ws + WS_OCCT, ws + WS_OCCLB);

  // s_c (overwrites Wsl/bs scratch)
  gemm_tn<<<dim3((KSLOT + 127) / 128, C_ / 64, B_), 256, 0, stream>>>(
      Amat, s, ws + WS_INVMAX, out + OFF_SC);

  repulsion_kernel<<<dim3(B_ * KSLOT), 256, 0, stream>>>(
      out + OFF_MU, out + OFF_SIG, ws + WS_REPB);

  final_scalars<<<dim3(1), 256, 0, stream>>>(
      ws + WS_ENTB, ws + WS_MSB, ws + WS_OCCLB, ws + WS_REPB, out + OFF_LOSS);
}

// Round 3
// 390.865 us; speedup vs baseline: 3.2098x; 3.2098x over previous
//
#include <hip/hip_runtime.h>
#include <math.h>

#define B_    4
#define N_    4096
#define C_    512
#define KSLOT 683

using bf16x8 = __attribute__((ext_vector_type(8))) short;
using f32x4  = __attribute__((ext_vector_type(4))) float;

// d_out layout (floats), concatenated in reference return order
#define OFF_A    0
#define OFF_SC   (B_*N_*KSLOT)
#define OFF_MU   (OFF_SC + B_*KSLOT*C_)
#define OFF_SIG  (OFF_MU + B_*KSLOT*3)
#define OFF_LOSS (OFF_SIG + B_*KSLOT*9)

// workspace float layout
#define WS_MOM    0
#define WS_INVMAX (WS_MOM + B_*KSLOT*16)
#define WS_OCCTB  (WS_INVMAX + B_*KSLOT)
#define WS_OCCT   (WS_OCCTB + 256)
#define WS_ENTB   (WS_OCCT + 4)
#define WS_MSB    (WS_ENTB + 256)
#define WS_OCCLB  (WS_MSB + 256)
#define WS_REPB   (WS_OCCLB + 256)
#define WS_BS     (WS_REPB + 256)
#define WS_FEND   (WS_BS + 704)          // 48432 floats

// workspace ushort (bf16) layout, offsets in ushorts from (ushort*)ws
#define US_BASE  (WS_FEND*2)                  // 96864 (16B aligned)
#define US_SBF   US_BASE                      // s_bf16   [B*N][C]
#define US_STF   (US_SBF + B_*N_*C_)          // sT_bf16  [B][C][N]
#define US_ATF   (US_STF + B_*C_*N_)          // At_bf16  [B][KSLOT][N]
#define US_WSL   (US_ATF + B_*KSLOT*N_)       // Wsl_bf16 [KSLOT][C]
#define US_END   (US_WSL + KSLOT*C_)

// ---------------- helpers ----------------

__device__ __forceinline__ ushort f2bf(float x) {
  union { float f; unsigned u; } v; v.f = x;
  unsigned r = v.u + 0x7fffu + ((v.u >> 16) & 1u);
  return (ushort)(r >> 16);
}

__device__ __forceinline__ float blockSum256(float v, float* red) {
#pragma unroll
  for (int off = 32; off; off >>= 1) v += __shfl_xor(v, off);
  __syncthreads();
  if ((threadIdx.x & 63) == 0) red[threadIdx.x >> 6] = v;
  __syncthreads();
  return red[0] + red[1] + red[2] + red[3];
}

__device__ __forceinline__ void top4_insert(float v, float& t0, float& t1, float& t2, float& t3) {
  if (v > t3) {
    if (v > t2) {
      t3 = t2;
      if (v > t1) {
        t2 = t1;
        if (v > t0) { t1 = t0; t0 = v; } else t1 = v;
      } else t2 = v;
    } else t3 = v;
  }
}

// ---------------- s -> s_bf16 and sT_bf16 (tiled transpose+convert) ----------------
__global__ __launch_bounds__(256) void convert_s_kernel(const float* __restrict__ s,
                                                        ushort* __restrict__ sbf,
                                                        ushort* __restrict__ stf) {
  __shared__ float T[32][33];
  const int b = blockIdx.z;
  const int n0 = blockIdx.x * 32, c0 = blockIdx.y * 32;
  const int t = threadIdx.x;
  const int r = t >> 3, q4 = (t & 7) * 4;
  float4 v = *(const float4*)(s + ((size_t)(b * N_ + n0 + r)) * C_ + c0 + q4);
  ushort4 u;
  u.x = f2bf(v.x); u.y = f2bf(v.y); u.z = f2bf(v.z); u.w = f2bf(v.w);
  *(ushort4*)(sbf + ((size_t)(b * N_ + n0 + r)) * C_ + c0 + q4) = u;
  T[q4 + 0][r] = v.x; T[q4 + 1][r] = v.y; T[q4 + 2][r] = v.z; T[q4 + 3][r] = v.w;
  __syncthreads();
  ushort4 o;
  o.x = f2bf(T[r][q4 + 0]); o.y = f2bf(T[r][q4 + 1]);
  o.z = f2bf(T[r][q4 + 2]); o.w = f2bf(T[r][q4 + 3]);
  *(ushort4*)(stf + ((size_t)(b * C_ + c0 + r)) * N_ + n0 + q4) = o;
}

// ---------------- A (post-softmax) -> At_bf16 [b][k][n] ----------------
__global__ __launch_bounds__(256) void transpose_A_kernel(const float* __restrict__ Amat,
                                                          ushort* __restrict__ atf) {
  __shared__ float T[32][33];
  const int b = blockIdx.z;
  const int n0 = blockIdx.x * 32, k0 = blockIdx.y * 32;
  const int t = threadIdx.x;
  const int r = t >> 3, q4 = (t & 7) * 4;
  const float* arow = Amat + ((size_t)(b * N_ + n0 + r)) * KSLOT;
#pragma unroll
  for (int i = 0; i < 4; ++i) {
    int k = k0 + q4 + i;
    T[q4 + i][r] = (k < KSLOT) ? arow[k] : 0.f;
  }
  __syncthreads();
  int k = k0 + r;
  if (k < KSLOT) {
    ushort4 o;
    o.x = f2bf(T[r][q4 + 0]); o.y = f2bf(T[r][q4 + 1]);
    o.z = f2bf(T[r][q4 + 2]); o.w = f2bf(T[r][q4 + 3]);
    *(ushort4*)(atf + ((size_t)(b * KSLOT + k)) * N_ + n0 + q4) = o;
  }
}

// ---------------- Wsl_bf16[k,c] = bf16( sum_d slots[k,d] * W[d,c] ) ----------------
__global__ __launch_bounds__(256) void wslots_bf16_kernel(const float* __restrict__ slots,
                                                          const float* __restrict__ W,
                                                          ushort* __restrict__ wsl) {
  __shared__ float SL[8][512];
  const int k0 = blockIdx.x * 8;
  const int c = blockIdx.y * 256 + threadIdx.x;
  for (int idx = threadIdx.x; idx < 8 * 512; idx += 256) {
    int kk = idx >> 9, d = idx & 511;
    SL[kk][d] = (k0 + kk < KSLOT) ? slots[(size_t)(k0 + kk) * C_ + d] : 0.f;
  }
  __syncthreads();
  float acc[8];
#pragma unroll
  for (int i = 0; i < 8; ++i) acc[i] = 0.f;
  for (int d = 0; d < C_; ++d) {
    float w = W[(size_t)d * C_ + c];
#pragma unroll
    for (int i = 0; i < 8; ++i) acc[i] += SL[i][d] * w;
  }
#pragma unroll
  for (int i = 0; i < 8; ++i)
    if (k0 + i < KSLOT) wsl[(size_t)(k0 + i) * C_ + c] = f2bf(acc[i]);
}

// bs[k] = sum_d slots[k,d] * b[d]
__global__ __launch_bounds__(256) void bs_kernel(const float* __restrict__ slots,
                                                 const float* __restrict__ bvec,
                                                 float* __restrict__ bs) {
  int k = blockIdx.x * 256 + threadIdx.x;
  if (k >= KSLOT) return;
  const float* srow = slots + (size_t)k * C_;
  float acc = 0.f;
  for (int d = 0; d < C_; ++d) acc += srow[d] * bvec[d];
  bs[k] = acc;
}

// ---------------- MFMA GEMM1: logits[m, k] = sum_c sbf[m,c]*wsl[k,c] + bs[k] ----------------
// 128x128 tile, BK=64 (128B LDS rows, bijective st_16x32 swizzle), 4 waves (2x2)
__global__ __launch_bounds__(256) void gemm1_mfma(const ushort* __restrict__ sbf,
                                                  const ushort* __restrict__ wsl,
                                                  const float* __restrict__ bs,
                                                  float* __restrict__ logits) {
  __shared__ __align__(16) ushort As[128 * 64];
  __shared__ __align__(16) ushort Bs[128 * 64];
  const int t = threadIdx.x;
  const int lane = t & 63;
  const int w = t >> 6;
  const int wm = w >> 1, wn = w & 1;
  const int m0 = blockIdx.x * 128, n0 = blockIdx.y * 128;
  f32x4 zero = {0.f, 0.f, 0.f, 0.f};
  f32x4 acc[4][4];
#pragma unroll
  for (int i = 0; i < 4; ++i)
#pragma unroll
    for (int j = 0; j < 4; ++j) acc[i][j] = zero;

  const int lrow = t >> 3;  // 0..31
  const int lch = t & 7;    // 16B chunk 0..7 within 128B row
  for (int k0 = 0; k0 < C_; k0 += 64) {
#pragma unroll
    for (int p = 0; p < 4; ++p) {
      int row = lrow + p * 32;
      int off = row * 128 + ((lch * 16) ^ ((row & 7) << 4));
      uint4 va = *(const uint4*)(sbf + (size_t)(m0 + row) * C_ + k0 + lch * 8);
      *(uint4*)((char*)As + off) = va;
      int brow = n0 + row;
      uint4 vb = {0u, 0u, 0u, 0u};
      if (brow < KSLOT) vb = *(const uint4*)(wsl + (size_t)brow * C_ + k0 + lch * 8);
      *(uint4*)((char*)Bs + off) = vb;
    }
    __syncthreads();
#pragma unroll
    for (int kk = 0; kk < 2; ++kk) {
      bf16x8 af[4], bfv[4];
      const int ach = kk * 4 + (lane >> 4);
#pragma unroll
      for (int i = 0; i < 4; ++i) {
        int ar = wm * 64 + i * 16 + (lane & 15);
        af[i] = *(const bf16x8*)((char*)As + ar * 128 + ((ach * 16) ^ ((ar & 7) << 4)));
        int br = wn * 64 + i * 16 + (lane & 15);
        bfv[i] = *(const bf16x8*)((char*)Bs + br * 128 + ((ach * 16) ^ ((br & 7) << 4)));
      }
#pragma unroll
      for (int i = 0; i < 4; ++i)
#pragma unroll
        for (int j = 0; j < 4; ++j)
          acc[i][j] = __builtin_amdgcn_mfma_f32_16x16x32_bf16(af[i], bfv[j], acc[i][j], 0, 0, 0);
    }
    __syncthreads();
  }
  const int rbase = m0 + wm * 64 + (lane >> 4) * 4;
  const int cbase = n0 + wn * 64 + (lane & 15);
#pragma unroll
  for (int j = 0; j < 4; ++j) {
    int col = cbase + j * 16;
    if (col >= KSLOT) continue;
    float bias = bs[col];
#pragma unroll
    for (int i = 0; i < 4; ++i)
#pragma unroll
      for (int r = 0; r < 4; ++r)
        logits[(size_t)(rbase + i * 16 + r) * KSLOT + col] = acc[i][j][r] + bias;
  }
}

// ---------------- MFMA GEMM2: s_c[b,k,c] += invmax[b,k] * sum_n At[b,k,n]*sT[b,c,n] ----------------
// split over n (8 splits of 512), fp32 atomicAdd into zeroed output
#define NSPLIT 8
__global__ __launch_bounds__(256) void gemm2_mfma(const ushort* __restrict__ atf,
                                                  const ushort* __restrict__ stf,
                                                  const float* __restrict__ invmax,
                                                  float* __restrict__ sc) {
  __shared__ __align__(16) ushort As[128 * 64];
  __shared__ __align__(16) ushort Bs[128 * 64];
  const int t = threadIdx.x;
  const int lane = t & 63;
  const int w = t >> 6;
  const int wm = w >> 1, wn = w & 1;
  const int b = blockIdx.z >> 3, sp = blockIdx.z & 7;
  const int m0 = blockIdx.x * 128, n0 = blockIdx.y * 128;
  const ushort* Ab = atf + (size_t)b * KSLOT * N_;
  const ushort* Bb = stf + (size_t)b * C_ * N_;
  f32x4 zero = {0.f, 0.f, 0.f, 0.f};
  f32x4 acc[4][4];
#pragma unroll
  for (int i = 0; i < 4; ++i)
#pragma unroll
    for (int j = 0; j < 4; ++j) acc[i][j] = zero;

  const int lrow = t >> 3;
  const int lch = t & 7;
  const int r0 = sp * (N_ / NSPLIT);
  for (int k0 = r0; k0 < r0 + N_ / NSPLIT; k0 += 64) {
#pragma unroll
    for (int p = 0; p < 4; ++p) {
      int row = lrow + p * 32;
      int off = row * 128 + ((lch * 16) ^ ((row & 7) << 4));
      int arow = m0 + row;
      uint4 va = {0u, 0u, 0u, 0u};
      if (arow < KSLOT) va = *(const uint4*)(Ab + (size_t)arow * N_ + k0 + lch * 8);
      *(uint4*)((char*)As + off) = va;
      uint4 vb = *(const uint4*)(Bb + (size_t)(n0 + row) * N_ + k0 + lch * 8);
      *(uint4*)((char*)Bs + off) = vb;
    }
    __syncthreads();
#pragma unroll
    for (int kk = 0; kk < 2; ++kk) {
      bf16x8 af[4], bfv[4];
      const int ach = kk * 4 + (lane >> 4);
#pragma unroll
      for (int i = 0; i < 4; ++i) {
        int ar = wm * 64 + i * 16 + (lane & 15);
        af[i] = *(const bf16x8*)((char*)As + ar * 128 + ((ach * 16) ^ ((ar & 7) << 4)));
        int br = wn * 64 + i * 16 + (lane & 15);
        bfv[i] = *(const bf16x8*)((char*)Bs + br * 128 + ((ach * 16) ^ ((br & 7) << 4)));
      }
#pragma unroll
      for (int i = 0; i < 4; ++i)
#pragma unroll
        for (int j = 0; j < 4; ++j)
          acc[i][j] = __builtin_amdgcn_mfma_f32_16x16x32_bf16(af[i], bfv[j], acc[i][j], 0, 0, 0);
    }
    __syncthreads();
  }
  const int rbase = m0 + wm * 64 + (lane >> 4) * 4;
  const int cbase = n0 + wn * 64 + (lane & 15);
#pragma unroll
  for (int i = 0; i < 4; ++i)
#pragma unroll
    for (int r = 0; r < 4; ++r) {
      int krow = rbase + i * 16 + r;
      if (krow >= KSLOT) continue;
      float sv = invmax[(size_t)b * KSLOT + krow];
      float* dst = sc + ((size_t)(b * KSLOT + krow)) * C_;
#pragma unroll
      for (int j = 0; j < 4; ++j)
        atomicAdd(&dst[cbase + j * 16], acc[i][j][r] * sv);
    }
}

// ---------------- masked softmax over K + entropy accumulation (in place) ----------------
__global__ __launch_bounds__(256) void softmax_rows(float* __restrict__ Amat,
                                                    const float* __restrict__ mask,
                                                    float* __restrict__ entb,
                                                    float* __restrict__ msb) {
  __shared__ float red[4];
  const int row = blockIdx.x;
  const int tid = threadIdx.x;
  float* rowp = Amat + (size_t)row * KSLOT;
  const float m = mask[row];
  const bool msk = (m < 0.5f);
  float v[3];
#pragma unroll
  for (int i = 0; i < 3; ++i) {
    int k = tid + i * 256;
    if (k < KSLOT) {
      float l = rowp[k];
      v[i] = msk ? -1e9f : l;
    } else v[i] = -3.0e38f;
  }
  float lmax = fmaxf(fmaxf(v[0], v[1]), v[2]);
#pragma unroll
  for (int off = 32; off; off >>= 1) lmax = fmaxf(lmax, __shfl_xor(lmax, off));
  __syncthreads();
  if ((tid & 63) == 0) red[tid >> 6] = lmax;
  __syncthreads();
  lmax = fmaxf(fmaxf(red[0], red[1]), fmaxf(red[2], red[3]));

  float lsum = 0.f;
#pragma unroll
  for (int i = 0; i < 3; ++i) {
    int k = tid + i * 256;
    float e = (k < KSLOT) ? expf(v[i] - lmax) : 0.f;
    v[i] = e;
    lsum += e;
  }
  lsum = blockSum256(lsum, red);
  float inv = 1.f / lsum;
  float ent = 0.f;
#pragma unroll
  for (int i = 0; i < 3; ++i) {
    int k = tid + i * 256;
    if (k < KSLOT) {
      float a = v[i] * inv * m;
      rowp[k] = a;
      float ac = fmaxf(a, 1e-8f);
      ent -= ac * logf(ac);
    }
  }
  ent = blockSum256(ent, red);
  if (tid == 0) {
    int bin = blockIdx.x & 255;
    atomicAdd(&entb[bin], ent * m);
    atomicAdd(&msb[bin], m);
  }
}

// ---------------- moment accumulation ----------------
__global__ __launch_bounds__(256) void moments_kernel(const float* __restrict__ Amat,
                                                      const float* __restrict__ mu,
                                                      const float* __restrict__ Sig,
                                                      float* __restrict__ MOM) {
  const int b = blockIdx.z;
  const int kx = threadIdx.x & 63;
  const int k = blockIdx.x * 64 + kx;
  const int ng = threadIdx.x >> 6;
  const int n0 = blockIdx.y * 256;
  const bool valid = (k < KSLOT);
  float acc[16];
#pragma unroll
  for (int i = 0; i < 16; ++i) acc[i] = 0.f;

  for (int nn = ng; nn < 256; nn += 4) {
    const int n = n0 + nn;
    const float a = valid ? Amat[((size_t)b * N_ + n) * KSLOT + k] : 0.f;
    const float* mup = mu + ((size_t)b * N_ + n) * 3;
    const float m0v = mup[0], m1v = mup[1], m2v = mup[2];
    const float* sp = Sig + ((size_t)b * N_ + n) * 9;
    acc[0] += a;
    acc[1] += a * m0v; acc[2] += a * m1v; acc[3] += a * m2v;
    acc[4] += a * m0v * m0v; acc[5] += a * m0v * m1v; acc[6] += a * m0v * m2v;
    acc[7] += a * m1v * m1v; acc[8] += a * m1v * m2v; acc[9] += a * m2v * m2v;
    acc[10] += a * sp[0]; acc[11] += a * sp[1]; acc[12] += a * sp[2];
    acc[13] += a * sp[4]; acc[14] += a * sp[5]; acc[15] += a * sp[8];
  }
  __shared__ float red[64][16];
  if (ng == 0) {
#pragma unroll
    for (int i = 0; i < 16; ++i) red[kx][i] = acc[i];
  }
  __syncthreads();
  if (ng == 1) {
#pragma unroll
    for (int i = 0; i < 16; ++i) red[kx][i] += acc[i];
  }
  __syncthreads();
  if (ng == 2) {
#pragma unroll
    for (int i = 0; i < 16; ++i) red[kx][i] += acc[i];
  }
  __syncthreads();
  if (ng == 3) {
#pragma unroll
    for (int i = 0; i < 16; ++i) red[kx][i] += acc[i];
  }
  __syncthreads();
  if (ng == 0 && valid) {
    float* dst = MOM + ((size_t)b * KSLOT + k) * 16;
#pragma unroll
    for (int i = 0; i < 16; ++i) atomicAdd(&dst[i], red[kx][i]);
  }
}

// ---------------- finalize per (b,k) ----------------
__global__ __launch_bounds__(256) void finalize_bk(const float* __restrict__ MOM,
                                                   float* __restrict__ muc,
                                                   float* __restrict__ sigc,
                                                   float* __restrict__ invmax,
                                                   float* __restrict__ occtb) {
  int bk = blockIdx.x * 256 + threadIdx.x;
  if (bk >= B_ * KSLOT) return;
  int b = bk / KSLOT;
  const float* T = MOM + (size_t)bk * 16;
  float den = T[0];
  float inv_eps = 1.f / (den + 1e-8f);
  float inv_mx = 1.f / fmaxf(den, 1e-8f);
  float mc0 = T[1] * inv_eps, mc1 = T[2] * inv_eps, mc2 = T[3] * inv_eps;
  float M0 = den * inv_eps;
  float cf = 2.f - M0;
  float S00 = (T[10] + T[4]) * inv_eps - cf * mc0 * mc0;
  float S01 = (T[11] + T[5]) * inv_eps - cf * mc0 * mc1;
  float S02 = (T[12] + T[6]) * inv_eps - cf * mc0 * mc2;
  float S11 = (T[13] + T[7]) * inv_eps - cf * mc1 * mc1;
  float S12 = (T[14] + T[8]) * inv_eps - cf * mc1 * mc2;
  float S22 = (T[15] + T[9]) * inv_eps - cf * mc2 * mc2;
  muc[(size_t)bk * 3 + 0] = mc0;
  muc[(size_t)bk * 3 + 1] = mc1;
  muc[(size_t)bk * 3 + 2] = mc2;
  float* sg = sigc + (size_t)bk * 9;
  sg[0] = S00; sg[1] = S01; sg[2] = S02;
  sg[3] = S01; sg[4] = S11; sg[5] = S12;
  sg[6] = S02; sg[7] = S12; sg[8] = S22;
  invmax[bk] = inv_mx;
  atomicAdd(&occtb[b * 64 + (threadIdx.x & 63)], den);
}

__global__ void reduce_occT(const float* __restrict__ bins, float* __restrict__ occT) {
  int tid = threadIdx.x;
  float v = bins[tid];
#pragma unroll
  for (int off = 32; off; off >>= 1) v += __shfl_xor(v, off);
  if ((tid & 63) == 0) occT[tid >> 6] = v;
}

__global__ __launch_bounds__(256) void occ_loss_kernel(const float* __restrict__ MOM,
                                                       const float* __restrict__ occT,
                                                       float* __restrict__ occlb) {
  __shared__ float red[4];
  int bk = blockIdx.x * 256 + threadIdx.x;
  float d2 = 0.f;
  if (bk < B_ * KSLOT) {
    int b = bk / KSLOT;
    float den = MOM[(size_t)bk * 16];
    float occ = den / fmaxf(occT[b], 1e-8f);
    float d = occ - (1.f / (float)KSLOT);
    d2 = d * d;
  }
  float ssum = blockSum256(d2, red);
  if (threadIdx.x == 0) occlb[blockIdx.x] = ssum;
}

// ---------------- repulsion ----------------
__global__ __launch_bounds__(256) void repulsion_kernel(const float* __restrict__ muc,
                                                        const float* __restrict__ sigc,
                                                        float* __restrict__ repb) {
  const int bp = blockIdx.x;
  const int b = bp / KSLOT;
  const int p = bp - b * KSLOT;
  const int tid = threadIdx.x;
  const float mp0 = muc[(size_t)bp * 3 + 0];
  const float mp1 = muc[(size_t)bp * 3 + 1];
  const float mp2 = muc[(size_t)bp * 3 + 2];
  const float* sgp = sigc + (size_t)bp * 9;
  const float pa = sgp[0], pb = sgp[1], pc = sgp[2], pd = sgp[4], pe = sgp[5], pf = sgp[8];
  float t0 = -3e38f, t1 = -3e38f, t2 = -3e38f, t3 = -3e38f;
  for (int q = tid; q < KSLOT; q += 256) {
    if (q == p) continue;
    const int bq = b * KSLOT + q;
    float d0 = mp0 - muc[(size_t)bq * 3 + 0];
    float d1 = mp1 - muc[(size_t)bq * 3 + 1];
    float d2 = mp2 - muc[(size_t)bq * 3 + 2];
    const float* sgq = sigc + (size_t)bq * 9;
    float a = pa + sgq[0] + 1e-6f;
    float bb = pb + sgq[1];
    float cc = pc + sgq[2];
    float d = pd + sgq[4] + 1e-6f;
    float e = pe + sgq[5];
    float f = pf + sgq[8] + 1e-6f;
    float C00 = d * f - e * e;
    float C01 = cc * e - bb * f;
    float C02 = bb * e - cc * d;
    float C11 = a * f - cc * cc;
    float C12 = bb * cc - a * e;
    float C22 = a * d - bb * bb;
    float det = a * C00 + bb * C01 + cc * C02;
    float dist2 = (C00 * d0 * d0 + C11 * d1 * d1 + C22 * d2 * d2 +
                   2.f * (C01 * d0 * d1 + C02 * d0 * d2 + C12 * d1 * d2)) / det;
    top4_insert(-0.5f * dist2, t0, t1, t2, t3);
  }
  __shared__ float tl[256][4];
  __shared__ float wl[4][4];
  tl[tid][0] = t0; tl[tid][1] = t1; tl[tid][2] = t2; tl[tid][3] = t3;
  __syncthreads();
  if ((tid & 63) == 0) {
    int w = tid >> 6;
    float u0 = -3e38f, u1 = -3e38f, u2 = -3e38f, u3 = -3e38f;
    for (int i = w * 64; i < w * 64 + 64; ++i) {
      top4_insert(tl[i][0], u0, u1, u2, u3);
      top4_insert(tl[i][1], u0, u1, u2, u3);
      top4_insert(tl[i][2], u0, u1, u2, u3);
      top4_insert(tl[i][3], u0, u1, u2, u3);
    }
    wl[w][0] = u0; wl[w][1] = u1; wl[w][2] = u2; wl[w][3] = u3;
  }
  __syncthreads();
  if (tid == 0) {
    float u0 = -3e38f, u1 = -3e38f, u2 = -3e38f, u3 = -3e38f;
#pragma unroll
    for (int w = 0; w < 4; ++w)
#pragma unroll
      for (int j = 0; j < 4; ++j) top4_insert(wl[w][j], u0, u1, u2, u3);
    float s = fmaxf(u0 + 1.f, 0.f) + fmaxf(u1 + 1.f, 0.f) +
              fmaxf(u2 + 1.f, 0.f) + fmaxf(u3 + 1.f, 0.f);
    atomicAdd(&repb[blockIdx.x & 255], s);
  }
}

// ---------------- final scalars ----------------
__global__ __launch_bounds__(256) void final_scalars(const float* __restrict__ entb,
                                                     const float* __restrict__ msb,
                                                     const float* __restrict__ occlb,
                                                     const float* __restrict__ repb,
                                                     float* __restrict__ out) {
  __shared__ float red[4];
  int tid = threadIdx.x;
  float e = blockSum256(entb[tid], red);
  float ms = blockSum256(msb[tid], red);
  float oc = blockSum256(occlb[tid], red);
  float rp = blockSum256(repb[tid], red);
  if (tid == 0) {
    float loss_ent = e / fmaxf(ms, 1.f);
    float loss_occ = oc / (float)(B_ * KSLOT);
    float loss_rep = rp / (float)(B_ * KSLOT * 4);
    out[0] = loss_occ;
    out[1] = loss_rep;
    out[2] = loss_ent;
    out[3] = 1.0f * loss_occ + 0.1f * loss_rep + 0.01f * loss_ent;
  }
}

// ================= fp32 fallback GEMMs (used only if ws too small) =================

__global__ __launch_bounds__(256) void wslots_kernel(const float* __restrict__ slots,
                                                     const float* __restrict__ W,
                                                     float* __restrict__ Wsl) {
  int k = blockIdx.x;
  int c = blockIdx.y * 256 + threadIdx.x;
  const float* srow = slots + (size_t)k * C_;
  float acc = 0.f;
  for (int d = 0; d < C_; d += 4) {
    acc += srow[d] * W[(size_t)d * C_ + c];
    acc += srow[d + 1] * W[(size_t)(d + 1) * C_ + c];
    acc += srow[d + 2] * W[(size_t)(d + 2) * C_ + c];
    acc += srow[d + 3] * W[(size_t)(d + 3) * C_ + c];
  }
  Wsl[(size_t)k * C_ + c] = acc;
}

__global__ __launch_bounds__(256) void gemm_nt(const float* __restrict__ Am,
                                               const float* __restrict__ Bm,
                                               const float* __restrict__ bias,
                                               float* __restrict__ Cm,
                                               int M, int Nout, int Kd,
                                               int lda, int ldb, int ldc) {
  __shared__ float As[16][132];
  __shared__ float Bs[16][132];
  const int tid = threadIdx.x;
  const int tx = tid & 15, ty = tid >> 4;
  const int m0 = blockIdx.x * 128, n0 = blockIdx.y * 128;
  float acc[8][8];
#pragma unroll
  for (int i = 0; i < 8; ++i)
#pragma unroll
    for (int j = 0; j < 8; ++j) acc[i][j] = 0.f;
  const int r = tid >> 1, hc = (tid & 1) * 8;
  for (int k0 = 0; k0 < Kd; k0 += 16) {
    float va[8], vb[8];
    int gm = m0 + r;
    if (gm < M) {
      const float* p = Am + (size_t)gm * lda + k0 + hc;
      *(float4*)(va) = *(const float4*)(p);
      *(float4*)(va + 4) = *(const float4*)(p + 4);
    } else {
#pragma unroll
      for (int i = 0; i < 8; ++i) va[i] = 0.f;
    }
    int gn = n0 + r;
    if (gn < Nout) {
      const float* p = Bm + (size_t)gn * ldb + k0 + hc;
      *(float4*)(vb) = *(const float4*)(p);
      *(float4*)(vb + 4) = *(const float4*)(p + 4);
    } else {
#pragma unroll
      for (int i = 0; i < 8; ++i) vb[i] = 0.f;
    }
#pragma unroll
    for (int i = 0; i < 8; ++i) As[hc + i][r] = va[i];
#pragma unroll
    for (int i = 0; i < 8; ++i) Bs[hc + i][r] = vb[i];
    __syncthreads();
#pragma unroll
    for (int kk = 0; kk < 16; ++kk) {
      float a[8], bb[8];
      *(float4*)(a) = *(const float4*)&As[kk][ty * 8];
      *(float4*)(a + 4) = *(const float4*)&As[kk][ty * 8 + 4];
      *(float4*)(bb) = *(const float4*)&Bs[kk][tx * 8];
      *(float4*)(bb + 4) = *(const float4*)&Bs[kk][tx * 8 + 4];
#pragma unroll
      for (int i = 0; i < 8; ++i)
#pragma unroll
        for (int j = 0; j < 8; ++j) acc[i][j] += a[i] * bb[j];
    }
    __syncthreads();
  }
#pragma unroll
  for (int i = 0; i < 8; ++i) {
    int gm = m0 + ty * 8 + i;
    if (gm >= M) continue;
    float* crow = Cm + (size_t)gm * ldc;
#pragma unroll
    for (int j = 0; j < 8; ++j) {
      int gn = n0 + tx * 8 + j;
      if (gn < Nout) crow[gn] = acc[i][j] + bias[gn];
    }
  }
}

__global__ __launch_bounds__(256) void gemm_tn(const float* __restrict__ Aall,
                                               const float* __restrict__ Ball,
                                               const float* __restrict__ scale,
                                               float* __restrict__ Call) {
  const int b = blockIdx.z;
  const float* Am = Aall + (size_t)b * N_ * KSLOT;
  const float* Bv = Ball + (size_t)b * N_ * C_;
  float* Cm = Call + (size_t)b * KSLOT * C_;
  const float* sc = scale + (size_t)b * KSLOT;
  __shared__ float As[16][132];
  __shared__ float Bs[16][68];
  const int tid = threadIdx.x;
  const int tx = tid & 15, ty = tid >> 4;
  const int m0 = blockIdx.x * 128, n0 = blockIdx.y * 64;
  float acc[8][4];
#pragma unroll
  for (int i = 0; i < 8; ++i)
#pragma unroll
    for (int j = 0; j < 4; ++j) acc[i][j] = 0.f;
  const int rr = tid >> 4;
  const int mq = tid & 15;
  const int cq = (tid & 15) * 4;
  for (int r0 = 0; r0 < N_; r0 += 16) {
#pragma unroll
    for (int i = 0; i < 8; ++i) {
      int mm = mq + 16 * i;
      int gm = m0 + mm;
      As[rr][mm] = (gm < KSLOT) ? Am[(size_t)(r0 + rr) * KSLOT + gm] : 0.f;
    }
    *(float4*)&Bs[rr][cq] = *(const float4*)(Bv + (size_t)(r0 + rr) * C_ + n0 + cq);
    __syncthreads();
#pragma unroll
    for (int kk = 0; kk < 16; ++kk) {
      float a[8], bb[4];
      *(float4*)(a) = *(const float4*)&As[kk][ty * 8];
      *(float4*)(a + 4) = *(const float4*)&As[kk][ty * 8 + 4];
      *(float4*)(bb) = *(const float4*)&Bs[kk][tx * 4];
#pragma unroll
      for (int i = 0; i < 8; ++i)
#pragma unroll
        for (int j = 0; j < 4; ++j) acc[i][j] += a[i] * bb[j];
    }
    __syncthreads();
  }
#pragma unroll
  for (int i = 0; i < 8; ++i) {
    int gm = m0 + ty * 8 + i;
    if (gm < KSLOT) {
      float s = sc[gm];
      float4 v;
      v.x = acc[i][0] * s; v.y = acc[i][1] * s; v.z = acc[i][2] * s; v.w = acc[i][3] * s;
      *(float4*)(Cm + (size_t)gm * C_ + n0 + tx * 4) = v;
    }
  }
}

// ---------------- launch ----------------
extern "C" void kernel_launch(void* const* d_in, const int* in_sizes, int n_in,
                              void* d_out, int out_size, void* d_ws, size_t ws_size,
                              hipStream_t stream) {
  const float* s     = (const float*)d_in[0];
  const float* mu    = (const float*)d_in[1];
  const float* Sig   = (const float*)d_in[2];
  const float* mask  = (const float*)d_in[3];
  const float* W     = (const float*)d_in[4];
  const float* bvec  = (const float*)d_in[5];
  const float* slots = (const float*)d_in[6];
  float* out = (float*)d_out;
  float* ws  = (float*)d_ws;

  float* Amat = out + OFF_A;
  const bool fast = (ws_size >= (size_t)US_END * 2 + 64);

  (void)hipMemsetAsync(ws, 0, WS_FEND * sizeof(float), stream);
  bs_kernel<<<dim3(3), 256, 0, stream>>>(slots, bvec, ws + WS_BS);

  if (fast) {
    ushort* usw = (ushort*)ws;
    ushort* sbf = usw + US_SBF;
    ushort* stf = usw + US_STF;
    ushort* atf = usw + US_ATF;
    ushort* wsl = usw + US_WSL;

    (void)hipMemsetAsync(out + OFF_SC, 0, (size_t)B_ * KSLOT * C_ * sizeof(float), stream);

    convert_s_kernel<<<dim3(N_ / 32, C_ / 32, B_), 256, 0, stream>>>(s, sbf, stf);
    wslots_bf16_kernel<<<dim3((KSLOT + 7) / 8, C_ / 256), 256, 0, stream>>>(slots, W, wsl);

    gemm1_mfma<<<dim3((B_ * N_) / 128, (KSLOT + 127) / 128), 256, 0, stream>>>(
        sbf, wsl, ws + WS_BS, Amat);

    softmax_rows<<<dim3(B_ * N_), 256, 0, stream>>>(Amat, mask, ws + WS_ENTB, ws + WS_MSB);

    moments_kernel<<<dim3((KSLOT + 63) / 64, N_ / 256, B_), 256, 0, stream>>>(
        Amat, mu, Sig, ws + WS_MOM);

    transpose_A_kernel<<<dim3(N_ / 32, (KSLOT + 31) / 32, B_), 256, 0, stream>>>(Amat, atf);

    finalize_bk<<<dim3((B_ * KSLOT + 255) / 256), 256, 0, stream>>>(
        ws + WS_MOM, out + OFF_MU, out + OFF_SIG, ws + WS_INVMAX, ws + WS_OCCTB);

    reduce_occT<<<dim3(1), 256, 0, stream>>>(ws + WS_OCCTB, ws + WS_OCCT);
    occ_loss_kernel<<<dim3((B_ * KSLOT + 255) / 256), 256, 0, stream>>>(
        ws + WS_MOM, ws + WS_OCCT, ws + WS_OCCLB);

    gemm2_mfma<<<dim3((KSLOT + 127) / 128, C_ / 128, B_ * NSPLIT), 256, 0, stream>>>(
        atf, stf, ws + WS_INVMAX, out + OFF_SC);

    repulsion_kernel<<<dim3(B_ * KSLOT), 256, 0, stream>>>(
        out + OFF_MU, out + OFF_SIG, ws + WS_REPB);

    final_scalars<<<dim3(1), 256, 0, stream>>>(
        ws + WS_ENTB, ws + WS_MSB, ws + WS_OCCLB, ws + WS_REPB, out + OFF_LOSS);
  } else {
    float* Wsl = out + OFF_SC;

    wslots_kernel<<<dim3(KSLOT, 2), 256, 0, stream>>>(slots, W, Wsl);
    gemm_nt<<<dim3((B_ * N_) / 128, (KSLOT + 127) / 128), 256, 0, stream>>>(
        s, Wsl, ws + WS_BS, Amat, B_ * N_, KSLOT, C_, C_, C_, KSLOT);
    softmax_rows<<<dim3(B_ * N_), 256, 0, stream>>>(Amat, mask, ws + WS_ENTB, ws + WS_MSB);
    moments_kernel<<<dim3((KSLOT + 63) / 64, N_ / 256, B_), 256, 0, stream>>>(
        Amat, mu, Sig, ws + WS_MOM);
    finalize_bk<<<dim3((B_ * KSLOT + 255) / 256), 256, 0, stream>>>(
        ws + WS_MOM, out + OFF_MU, out + OFF_SIG, ws + WS_INVMAX, ws + WS_OCCTB);
    reduce_occT<<<dim3(1), 256, 0, stream>>>(ws + WS_OCCTB, ws + WS_OCCT);
    occ_loss_kernel<<<dim3((B_ * KSLOT + 255) / 256), 256, 0, stream>>>(
        ws + WS_MOM, ws + WS_OCCT, ws + WS_OCCLB);
    gemm_tn<<<dim3((KSLOT + 127) / 128, C_ / 64, B_), 256, 0, stream>>>(
        Amat, s, ws + WS_INVMAX, out + OFF_SC);
    repulsion_kernel<<<dim3(B_ * KSLOT), 256, 0, stream>>>(
        out + OFF_MU, out + OFF_SIG, ws + WS_REPB);
    final_scalars<<<dim3(1), 256, 0, stream>>>(
        ws + WS_ENTB, ws + WS_MSB, ws + WS_OCCLB, ws + WS_REPB, out + OFF_LOSS);
  }
}